// Round 6
// baseline (663.573 us; speedup 1.0000x reference)
//
#include <hip/hip_runtime.h>
#include <hip/hip_bf16.h>

#define NRBF 20

typedef __attribute__((ext_vector_type(8))) short short8;
typedef __attribute__((ext_vector_type(4))) float float4v;
typedef unsigned short ushort_t;

__device__ __forceinline__ float bf2f(ushort_t u) {
    return __uint_as_float(((unsigned)u) << 16);
}
__device__ __forceinline__ ushort_t f2bf(float f) {
    unsigned u = __float_as_uint(f);
    u += 0x7FFF + ((u >> 16) & 1);   // round-to-nearest-even
    return (ushort_t)(u >> 16);
}
__device__ __forceinline__ float ldin(const void* p, size_t idx, int isbf) {
    return isbf ? bf2f(((const ushort_t*)p)[idx]) : ((const float*)p)[idx];
}
__device__ __forceinline__ void stout(void* p, size_t idx, float v, int isbf) {
    if (isbf) ((ushort_t*)p)[idx] = f2bf(v);
    else      ((float*)p)[idx] = v;
}

// ---------------- dtype detector ----------------
__global__ void detect_kernel(const void* __restrict__ xyz, int* __restrict__ flag) {
    if (threadIdx.x == 0 && blockIdx.x == 0) {
        const ushort_t* u = (const ushort_t*)xyz;
        int bad = 0;
        for (int k = 0; k < 256; k++) {
            unsigned e = (u[2 * k] >> 7) & 0xFF;
            if (e >= 0x90) bad++;
        }
        *flag = (bad > 8) ? 0 : 1;  // 1 = bf16, 0 = f32
    }
}

// ---------------- prelude: fused degree-count (idx<E) + s init (idx<N*128) --------
__global__ void prelude_kernel(const void* __restrict__ xyz, const int* __restrict__ nbr,
                               const void* __restrict__ cg_s,
                               float* __restrict__ s_acc, ushort_t* __restrict__ s_hi,
                               ushort_t* __restrict__ s_lo,
                               int* __restrict__ deg, int N128, int E,
                               const int* __restrict__ flagp) {
    int isbf = *flagp;
    int idx = blockIdx.x * blockDim.x + threadIdx.x;
    if (idx < E) {
        int i = nbr[2 * idx], j = nbr[2 * idx + 1];
        float dx = ldin(xyz, 3 * j,     isbf) - ldin(xyz, 3 * i,     isbf);
        float dy = ldin(xyz, 3 * j + 1, isbf) - ldin(xyz, 3 * i + 1, isbf);
        float dz = ldin(xyz, 3 * j + 2, isbf) - ldin(xyz, 3 * i + 2, isbf);
        float dist = sqrtf(dx * dx + dy * dy + dz * dz + 3e-15f);
        if (dist < 5.0f) atomicAdd(&deg[i], 1);
    }
    if (idx < N128) {
        float v = ldin(cg_s, idx, isbf);
        s_acc[idx] = v;
        ushort_t hi = f2bf(v);
        s_hi[idx] = hi;
        s_lo[idx] = f2bf(v - bf2f(hi));
    }
}

// ---------------- scan: rowptr from deg; deg becomes cursor ----------------
__global__ void scan_kernel(int* __restrict__ deg, int* __restrict__ rowptr, int N) {
    __shared__ int part[256];
    int t = threadIdx.x;
    int chunk = (N + 255) / 256;
    int lo = t * chunk, hi = min(lo + chunk, N);
    int s = 0;
    for (int i = lo; i < hi; i++) s += deg[i];
    part[t] = s;
    __syncthreads();
    for (int off = 1; off < 256; off <<= 1) {
        int v = (t >= off) ? part[t - off] : 0;
        __syncthreads();
        if (t >= off) part[t] += v;
        __syncthreads();
    }
    int base = (t == 0) ? 0 : part[t - 1];
    for (int i = lo; i < hi; i++) {
        rowptr[i] = base;
        int d = deg[i];
        deg[i] = base;
        base += d;
    }
    if (t == 0) rowptr[N] = part[255];
}

// ---------------- pack: geometry recompute + CSR scatter (pos-ordered) ----------
// writes jlist[pos], upos[pos]=(ux,uy,uz,env), rbf hi/lo bf16 [pos][32] (K-padded)
__global__ void pack_kernel(const void* __restrict__ xyz, const int* __restrict__ nbr,
                            int* __restrict__ cursor, int* __restrict__ jlist,
                            float4* __restrict__ upos,
                            ushort_t* __restrict__ rbfhi, ushort_t* __restrict__ rbflo,
                            int E, const int* __restrict__ flagp) {
    int isbf = *flagp;
    int e = blockIdx.x * blockDim.x + threadIdx.x;
    if (e >= E) return;
    int i = nbr[2 * e], j = nbr[2 * e + 1];
    float dx = ldin(xyz, 3 * j,     isbf) - ldin(xyz, 3 * i,     isbf);
    float dy = ldin(xyz, 3 * j + 1, isbf) - ldin(xyz, 3 * i + 1, isbf);
    float dz = ldin(xyz, 3 * j + 2, isbf) - ldin(xyz, 3 * i + 2, isbf);
    float dist = sqrtf(dx * dx + dy * dy + dz * dz + 3e-15f);
    if (!(dist < 5.0f)) return;
    constexpr float PI = 3.14159265358979323846f;
    float ev = 0.5f * (cosf(PI * dist * 0.2f) + 1.0f);
    int pos = atomicAdd(&cursor[i], 1);
    jlist[pos] = j;
    float inv = 1.0f / dist;
    upos[pos] = make_float4(dx * inv, dy * inv, dz * inv, ev);
    constexpr double EM5 = 0.006737946999085467;  // exp(-5)
    constexpr float MU0 = (float)EM5;
    constexpr float DMU = (float)((1.0 - EM5) / 19.0);
    constexpr float BETA = (float)(1.0 / ((0.1 * (1.0 - EM5)) * (0.1 * (1.0 - EM5))));
    float ed = expf(-dist);
    size_t rb = (size_t)pos * 32;
    #pragma unroll
    for (int k = 0; k < NRBF; k++) {
        float dmu = ed - (MU0 + k * DMU);
        float v = expf(-BETA * dmu * dmu);   // env NOT folded (applied in w epilogue)
        ushort_t hi = f2bf(v);
        rbfhi[rb + k] = hi;
        rbflo[rb + k] = f2bf(v - bf2f(hi));
    }
    #pragma unroll
    for (int k = NRBF; k < 32; k++) { rbfhi[rb + k] = 0; rbflo[rb + k] = 0; }
}

// ---------------- weight-fragment prep (split-bf16, MFMA B-operand order) ----------
// B1: [l][ks4][nt8][lane64][8], B2: [l][ks4][nt24][lane64][8], Wr: [l][nt24][lane64][8]
__global__ void prep_frags_kernel(const void* __restrict__ W1, const void* __restrict__ W2,
                                  const void* __restrict__ Wr,
                                  ushort_t* __restrict__ B1hi, ushort_t* __restrict__ B1lo,
                                  ushort_t* __restrict__ B2hi, ushort_t* __restrict__ B2lo,
                                  ushort_t* __restrict__ Wfhi, ushort_t* __restrict__ Wflo,
                                  const int* __restrict__ flagp) {
    int isbf = *flagp;
    int idx = blockIdx.x * blockDim.x + threadIdx.x;
    const int NW1 = 3 * 4 * 8 * 64;
    const int NW2 = 3 * 4 * 24 * 64;
    const int NWR = 3 * 24 * 64;
    if (idx < NW1) {
        int lane = idx & 63;
        int t = idx >> 6;
        int nt = t % 8; t /= 8;
        int ks = t % 4; int l = t / 4;
        int n = lane & 15, quad = lane >> 4;
        int col = nt * 16 + n;
        size_t base = (size_t)l * 128 * 128;
        size_t fo = (size_t)idx * 8;
        #pragma unroll
        for (int j = 0; j < 8; j++) {
            int k = ks * 32 + quad * 8 + j;
            float v = ldin(W1, base + (size_t)k * 128 + col, isbf);
            ushort_t hi = f2bf(v);
            B1hi[fo + j] = hi;
            B1lo[fo + j] = f2bf(v - bf2f(hi));
        }
    } else if (idx < NW1 + NW2) {
        int i2 = idx - NW1;
        int lane = i2 & 63;
        int t = i2 >> 6;
        int nt = t % 24; t /= 24;
        int ks = t % 4; int l = t / 4;
        int n = lane & 15, quad = lane >> 4;
        int col = nt * 16 + n;
        size_t base = (size_t)l * 128 * 384;
        size_t fo = (size_t)i2 * 8;
        #pragma unroll
        for (int j = 0; j < 8; j++) {
            int k = ks * 32 + quad * 8 + j;
            float v = ldin(W2, base + (size_t)k * 384 + col, isbf);
            ushort_t hi = f2bf(v);
            B2hi[fo + j] = hi;
            B2lo[fo + j] = f2bf(v - bf2f(hi));
        }
    } else if (idx < NW1 + NW2 + NWR) {
        int i2 = idx - NW1 - NW2;
        int lane = i2 & 63;
        int t = i2 >> 6;
        int nt = t % 24; int l = t / 24;
        int n = lane & 15, quad = lane >> 4;
        int col = nt * 16 + n;
        size_t fo = (size_t)i2 * 8;
        #pragma unroll
        for (int j = 0; j < 8; j++) {
            int k = quad * 8 + j;   // K=32, only k<20 real
            float v = (k < NRBF) ? ldin(Wr, ((size_t)l * NRBF + k) * 384 + col, isbf) : 0.f;
            ushort_t hi = f2bf(v);
            Wfhi[fo + j] = hi;
            Wflo[fo + j] = f2bf(v - bf2f(hi));
        }
    }
}

// ---------------- fused GEMM1+GEMM2: phi = silu(s@W1+b1)@W2 + b2 ----------------
// 256 thr = 4 waves, 64 rows/block; h stays in LDS (split hi/lo bf16).
__global__ __launch_bounds__(256) void gemm12_kernel(
    const ushort_t* __restrict__ s_hi, const ushort_t* __restrict__ s_lo,
    const ushort_t* __restrict__ B1hi, const ushort_t* __restrict__ B1lo,
    const void* __restrict__ b1, size_t b1off,
    const ushort_t* __restrict__ B2hi, const ushort_t* __restrict__ B2lo,
    const void* __restrict__ b2, size_t b2off,
    ushort_t* __restrict__ phi, int M, const int* __restrict__ flagp) {
    int isbf = *flagp;
    __shared__ ushort_t hhi[64][136];   // +8 pad: 16B-aligned rows, conflict-spread
    __shared__ ushort_t hlo[64][136];
    int tid = threadIdx.x;
    int wave = tid >> 6, lane = tid & 63;
    int m = lane & 15, quad = lane >> 4;
    int wr0 = wave * 16;
    int brow = blockIdx.x * 64;
    int row = brow + wr0 + m;
    short8 zero8 = {};
    {   // ---- phase 1: h = silu(s@W1 + b1) -> LDS
        float4v acc1[8] = {};
        #pragma unroll
        for (int ks = 0; ks < 4; ks++) {
            short8 ah = zero8, al = zero8;
            if (row < M) {
                size_t ao = (size_t)row * 128 + ks * 32 + quad * 8;
                ah = *reinterpret_cast<const short8*>(s_hi + ao);
                al = *reinterpret_cast<const short8*>(s_lo + ao);
            }
            #pragma unroll
            for (int nt = 0; nt < 8; nt++) {
                size_t fo = (((size_t)ks * 8 + nt) * 64 + lane) * 8;
                short8 bh = *reinterpret_cast<const short8*>(B1hi + fo);
                acc1[nt] = __builtin_amdgcn_mfma_f32_16x16x32_bf16(ah, bh, acc1[nt], 0, 0, 0);
                acc1[nt] = __builtin_amdgcn_mfma_f32_16x16x32_bf16(al, bh, acc1[nt], 0, 0, 0);
                if (!isbf) {
                    short8 bl = *reinterpret_cast<const short8*>(B1lo + fo);
                    acc1[nt] = __builtin_amdgcn_mfma_f32_16x16x32_bf16(ah, bl, acc1[nt], 0, 0, 0);
                }
            }
        }
        #pragma unroll
        for (int nt = 0; nt < 8; nt++) {
            int col = nt * 16 + m;
            float bv = ldin(b1, b1off + col, isbf);
            #pragma unroll
            for (int r = 0; r < 4; r++) {
                int lrow = wr0 + quad * 4 + r;
                float x = acc1[nt][r] + bv;
                x = x / (1.0f + expf(-x));  // silu
                ushort_t h = f2bf(x);
                hhi[lrow][col] = h;
                hlo[lrow][col] = f2bf(x - bf2f(h));
            }
        }
    }
    __syncthreads();
    {   // ---- phase 2: phi = h@W2 + b2
        float4v acc2[24] = {};
        #pragma unroll
        for (int ks = 0; ks < 4; ks++) {
            short8 ah = *reinterpret_cast<const short8*>(&hhi[wr0 + m][ks * 32 + quad * 8]);
            short8 al = *reinterpret_cast<const short8*>(&hlo[wr0 + m][ks * 32 + quad * 8]);
            #pragma unroll
            for (int nt = 0; nt < 24; nt++) {
                size_t fo = (((size_t)ks * 24 + nt) * 64 + lane) * 8;
                short8 bh = *reinterpret_cast<const short8*>(B2hi + fo);
                acc2[nt] = __builtin_amdgcn_mfma_f32_16x16x32_bf16(ah, bh, acc2[nt], 0, 0, 0);
                acc2[nt] = __builtin_amdgcn_mfma_f32_16x16x32_bf16(al, bh, acc2[nt], 0, 0, 0);
                if (!isbf) {
                    short8 bl = *reinterpret_cast<const short8*>(B2lo + fo);
                    acc2[nt] = __builtin_amdgcn_mfma_f32_16x16x32_bf16(ah, bl, acc2[nt], 0, 0, 0);
                }
            }
        }
        #pragma unroll
        for (int nt = 0; nt < 24; nt++) {
            int col = nt * 16 + m;
            float bv = ldin(b2, b2off + col, isbf);
            #pragma unroll
            for (int r = 0; r < 4; r++) {
                int orow = brow + wr0 + quad * 4 + r;
                if (orow < M) phi[(size_t)orow * 384 + col] = f2bf(acc2[nt][r] + bv);
            }
        }
    }
}

// ---------------- node kernel: per-node block; w via in-kernel MFMA -> LDS ---------
// Thread t owns features {t, t+128, t+256}. 16-edge chunks:
//   phase A: w = (rbf@Wr + br)*env via MFMA into LDS (wave w handles nt 12w..12w+11)
//   phase B: gather phi[j]/v[j], accumulate ds/dv in registers.
template <int L0, int LAST>
__global__ __launch_bounds__(128) void node_kernel(
    const int* __restrict__ rowptr, const int* __restrict__ jlist,
    const float4* __restrict__ upos,
    const ushort_t* __restrict__ rbfhi, const ushort_t* __restrict__ rbflo,
    const ushort_t* __restrict__ wfh, const ushort_t* __restrict__ wfl,
    const void* __restrict__ br, size_t broff,
    const ushort_t* __restrict__ phi,
    const float* __restrict__ v_old, const ushort_t* __restrict__ vh_old,
    float* __restrict__ s_acc, ushort_t* __restrict__ s_hi, ushort_t* __restrict__ s_lo,
    float* __restrict__ v_new, ushort_t* __restrict__ vh_new,
    void* __restrict__ out, int N, const int* __restrict__ flagp) {
    int isbf = *flagp;
    __shared__ ushort_t wlds[16][392];  // 16 edges x 384 cols (+8 pad)
    int tt = threadIdx.x;
    int wave = tt >> 6, lane = tt & 63;
    int m = lane & 15, quad = lane >> 4;
    int node = blockIdx.x;
    int start = __builtin_amdgcn_readfirstlane(rowptr[node]);
    int end   = __builtin_amdgcn_readfirstlane(rowptr[node + 1]);
    float dsv = 0.f, ax = 0.f, ay = 0.f, az = 0.f;
    for (int c0 = start; c0 < end; c0 += 16) {
        int cnt = min(16, end - c0);
        // phase A: MFMA w for edges c0..c0+15 (rows>=cnt produce harmless garbage)
        short8 arh = *reinterpret_cast<const short8*>(&rbfhi[(size_t)(c0 + m) * 32 + quad * 8]);
        float4v acc[12] = {};
        if (!isbf) {
            short8 arl = *reinterpret_cast<const short8*>(&rbflo[(size_t)(c0 + m) * 32 + quad * 8]);
            #pragma unroll
            for (int t2 = 0; t2 < 12; t2++) {
                size_t fo = (((size_t)(wave * 12 + t2)) * 64 + lane) * 8;
                short8 bh = *reinterpret_cast<const short8*>(wfh + fo);
                short8 bl = *reinterpret_cast<const short8*>(wfl + fo);
                acc[t2] = __builtin_amdgcn_mfma_f32_16x16x32_bf16(arh, bh, acc[t2], 0, 0, 0);
                acc[t2] = __builtin_amdgcn_mfma_f32_16x16x32_bf16(arl, bh, acc[t2], 0, 0, 0);
                acc[t2] = __builtin_amdgcn_mfma_f32_16x16x32_bf16(arh, bl, acc[t2], 0, 0, 0);
            }
        } else {
            #pragma unroll
            for (int t2 = 0; t2 < 12; t2++) {
                size_t fo = (((size_t)(wave * 12 + t2)) * 64 + lane) * 8;
                short8 bh = *reinterpret_cast<const short8*>(wfh + fo);
                acc[t2] = __builtin_amdgcn_mfma_f32_16x16x32_bf16(arh, bh, acc[t2], 0, 0, 0);
            }
        }
        int jv = 0;
        if (lane < cnt) jv = jlist[c0 + lane];
        #pragma unroll
        for (int t2 = 0; t2 < 12; t2++) {
            int col = (wave * 12 + t2) * 16 + m;
            float bb = ldin(br, broff + col, isbf);
            #pragma unroll
            for (int r = 0; r < 4; r++) {
                int erow = quad * 4 + r;
                float ev = upos[c0 + erow].w;
                wlds[erow][col] = f2bf((acc[t2][r] + bb) * ev);
            }
        }
        __syncthreads();
        // phase B: gather + accumulate
        for (int k = 0; k < cnt; k++) {
            int j = __shfl(jv, k);
            float4 u4 = upos[c0 + k];
            float w0 = bf2f(wlds[k][tt]);
            float w1 = bf2f(wlds[k][128 + tt]);
            float w2 = bf2f(wlds[k][256 + tt]);
            size_t jb = (size_t)j * 384;
            dsv += bf2f(phi[jb + tt]) * w0;
            float gv = bf2f(phi[jb + 128 + tt]) * w1;
            float gu = bf2f(phi[jb + 256 + tt]) * w2;
            if (L0) {
                ax += gu * u4.x; ay += gu * u4.y; az += gu * u4.z;
            } else {
                const ushort_t* vj = &vh_old[jb + (size_t)tt * 3];
                ax += gu * u4.x + gv * bf2f(vj[0]);
                ay += gu * u4.y + gv * bf2f(vj[1]);
                az += gu * u4.z + gv * bf2f(vj[2]);
            }
        }
        __syncthreads();
    }
    size_t so = (size_t)node * 128 + tt;
    float snew = s_acc[so] + dsv;
    size_t ib = (size_t)node * 384 + (size_t)tt * 3;
    float vx = L0 ? ax : v_old[ib]     + ax;
    float vy = L0 ? ay : v_old[ib + 1] + ay;
    float vz = L0 ? az : v_old[ib + 2] + az;
    if (LAST) {
        stout(out, so, snew, isbf);
        size_t ob = (size_t)N * 128 + ib;
        stout(out, ob,     vx, isbf);
        stout(out, ob + 1, vy, isbf);
        stout(out, ob + 2, vz, isbf);
    } else {
        s_acc[so] = snew;
        ushort_t hi = f2bf(snew);
        s_hi[so] = hi;
        s_lo[so] = f2bf(snew - bf2f(hi));
        v_new[ib] = vx; v_new[ib + 1] = vy; v_new[ib + 2] = vz;
        vh_new[ib]     = f2bf(vx);
        vh_new[ib + 1] = f2bf(vy);
        vh_new[ib + 2] = f2bf(vz);
    }
}

extern "C" void kernel_launch(void* const* d_in, const int* in_sizes, int n_in,
                              void* d_out, int out_size, void* d_ws, size_t ws_size,
                              hipStream_t stream) {
    const int N = in_sizes[0] / 3;
    const int E = in_sizes[1] / 2;
    const void* xyz  = d_in[0];
    const int*  nbr  = (const int*)d_in[1];
    const void* cg_s = d_in[2];
    const void* W1   = d_in[3];
    const void* b1   = d_in[4];
    const void* W2   = d_in[5];
    const void* b2   = d_in[6];
    const void* Wr   = d_in[7];
    const void* br   = d_in[8];

    // byte-offset allocator (64B aligned)
    size_t off = 0;
    auto alloc = [&](size_t bytes) -> char* {
        char* p = (char*)d_ws + off;
        off = (off + bytes + 63) & ~(size_t)63;
        return p;
    };
    int*      flag   = (int*)alloc(64);
    float*    s_acc  = (float*)alloc((size_t)N * 128 * 4);
    float*    vA     = (float*)alloc((size_t)N * 384 * 4);
    float*    vB     = (float*)alloc((size_t)N * 384 * 4);
    int*      rowptr = (int*)alloc((size_t)(N + 1) * 4);
    int*      deg    = (int*)alloc((size_t)N * 4);
    int*      jlist  = (int*)alloc((size_t)E * 4);
    float4*   upos   = (float4*)alloc((size_t)(E + 16) * 16);
    ushort_t* rbfhi  = (ushort_t*)alloc((size_t)(E + 16) * 32 * 2);
    ushort_t* rbflo  = (ushort_t*)alloc((size_t)(E + 16) * 32 * 2);
    ushort_t* s_hi   = (ushort_t*)alloc((size_t)N * 128 * 2);
    ushort_t* s_lo   = (ushort_t*)alloc((size_t)N * 128 * 2);
    ushort_t* phi    = (ushort_t*)alloc((size_t)N * 384 * 2);
    ushort_t* vhA    = (ushort_t*)alloc((size_t)N * 384 * 2);
    ushort_t* vhB    = (ushort_t*)alloc((size_t)N * 384 * 2);
    ushort_t* B1hi   = (ushort_t*)alloc((size_t)3 * 4 * 8 * 64 * 8 * 2);
    ushort_t* B1lo   = (ushort_t*)alloc((size_t)3 * 4 * 8 * 64 * 8 * 2);
    ushort_t* B2hi   = (ushort_t*)alloc((size_t)3 * 4 * 24 * 64 * 8 * 2);
    ushort_t* B2lo   = (ushort_t*)alloc((size_t)3 * 4 * 24 * 64 * 8 * 2);
    ushort_t* Wfhi   = (ushort_t*)alloc((size_t)3 * 24 * 64 * 8 * 2);
    ushort_t* Wflo   = (ushort_t*)alloc((size_t)3 * 24 * 64 * 8 * 2);

    detect_kernel<<<1, 64, 0, stream>>>(xyz, flag);
    hipMemsetAsync(deg, 0, (size_t)N * sizeof(int), stream);
    const int N128 = N * 128;
    const int pg = (max(E, N128) + 255) / 256;
    prelude_kernel<<<pg, 256, 0, stream>>>(xyz, nbr, cg_s, s_acc, s_hi, s_lo, deg, N128, E, flag);
    scan_kernel<<<1, 256, 0, stream>>>(deg, rowptr, N);
    pack_kernel<<<(E + 255) / 256, 256, 0, stream>>>(xyz, nbr, deg, jlist, upos, rbfhi, rbflo, E, flag);
    const int NPREP = 3 * 4 * 8 * 64 + 3 * 4 * 24 * 64 + 3 * 24 * 64;
    prep_frags_kernel<<<(NPREP + 255) / 256, 256, 0, stream>>>(
        W1, W2, Wr, B1hi, B1lo, B2hi, B2lo, Wfhi, Wflo, flag);

    const int gx = (N + 63) / 64;
    for (int l = 0; l < 3; l++) {
        gemm12_kernel<<<gx, 256, 0, stream>>>(
            s_hi, s_lo,
            B1hi + (size_t)l * 4 * 8 * 64 * 8, B1lo + (size_t)l * 4 * 8 * 64 * 8,
            b1, (size_t)l * 128,
            B2hi + (size_t)l * 4 * 24 * 64 * 8, B2lo + (size_t)l * 4 * 24 * 64 * 8,
            b2, (size_t)l * 384, phi, N, flag);
        const ushort_t* wfh = Wfhi + (size_t)l * 24 * 64 * 8;
        const ushort_t* wfl = Wflo + (size_t)l * 24 * 64 * 8;
        if (l == 0) {
            node_kernel<1, 0><<<N, 128, 0, stream>>>(
                rowptr, jlist, upos, rbfhi, rbflo, wfh, wfl, br, (size_t)l * 384,
                phi, vA, vhA, s_acc, s_hi, s_lo, vA, vhA, d_out, N, flag);
        } else if (l == 1) {
            node_kernel<0, 0><<<N, 128, 0, stream>>>(
                rowptr, jlist, upos, rbfhi, rbflo, wfh, wfl, br, (size_t)l * 384,
                phi, vA, vhA, s_acc, s_hi, s_lo, vB, vhB, d_out, N, flag);
        } else {
            node_kernel<0, 1><<<N, 128, 0, stream>>>(
                rowptr, jlist, upos, rbfhi, rbflo, wfh, wfl, br, (size_t)l * 384,
                phi, vB, vhB, s_acc, s_hi, s_lo, vB, vhB, d_out, N, flag);
        }
    }
}

// Round 7
// 539.735 us; speedup vs baseline: 1.2294x; 1.2294x over previous
//
#include <hip/hip_runtime.h>
#include <hip/hip_bf16.h>

#define NRBF 20

typedef __attribute__((ext_vector_type(8))) short short8;
typedef __attribute__((ext_vector_type(4))) float float4v;
typedef unsigned short ushort_t;

__device__ __forceinline__ float bf2f(ushort_t u) {
    return __uint_as_float(((unsigned)u) << 16);
}
__device__ __forceinline__ ushort_t f2bf(float f) {
    unsigned u = __float_as_uint(f);
    u += 0x7FFF + ((u >> 16) & 1);   // round-to-nearest-even
    return (ushort_t)(u >> 16);
}
__device__ __forceinline__ float ldin(const void* p, size_t idx, int isbf) {
    return isbf ? bf2f(((const ushort_t*)p)[idx]) : ((const float*)p)[idx];
}
__device__ __forceinline__ void stout(void* p, size_t idx, float v, int isbf) {
    if (isbf) ((ushort_t*)p)[idx] = f2bf(v);
    else      ((float*)p)[idx] = v;
}

// ---------------- dtype detect + deg zero (fused) ----------------
__global__ void detect_kernel(const void* __restrict__ xyz, int* __restrict__ flag,
                              int* __restrict__ deg, int N) {
    int idx = blockIdx.x * blockDim.x + threadIdx.x;
    if (idx < N) deg[idx] = 0;
    if (blockIdx.x == 0 && threadIdx.x < 64) {
        const ushort_t* u = (const ushort_t*)xyz;
        unsigned e0 = (u[2 * threadIdx.x] >> 7) & 0xFF;
        unsigned long long bad = __ballot(e0 >= 0x90);
        if (threadIdx.x == 0) *flag = (__popcll(bad) > 2) ? 0 : 1;  // 1=bf16, 0=f32
    }
}

// ---------------- prelude: deg count + s init + weight-frag prep ----------------
// Frag layouts: B1 [l][ks4][nt8][lane64][8]; B2 [l][ks4][nt24][lane64][8];
// Wr-aug [l][nt24][lane64][8] with K-row 20 = br (w = [rbf*env, env] @ [Wr; br]).
__global__ void prelude_kernel(const void* __restrict__ xyz, const int* __restrict__ nbr,
                               const void* __restrict__ cg_s,
                               const void* __restrict__ W1, const void* __restrict__ W2,
                               const void* __restrict__ Wr, const void* __restrict__ br,
                               float* __restrict__ s_acc, ushort_t* __restrict__ s_hi,
                               ushort_t* __restrict__ s_lo, int* __restrict__ deg,
                               ushort_t* __restrict__ B1hi, ushort_t* __restrict__ B1lo,
                               ushort_t* __restrict__ B2hi, ushort_t* __restrict__ B2lo,
                               ushort_t* __restrict__ Wfhi, ushort_t* __restrict__ Wflo,
                               int N128, int E, const int* __restrict__ flagp) {
    int isbf = *flagp;
    int idx = blockIdx.x * blockDim.x + threadIdx.x;
    if (idx < E) {
        int i = nbr[2 * idx], j = nbr[2 * idx + 1];
        float dx = ldin(xyz, 3 * j,     isbf) - ldin(xyz, 3 * i,     isbf);
        float dy = ldin(xyz, 3 * j + 1, isbf) - ldin(xyz, 3 * i + 1, isbf);
        float dz = ldin(xyz, 3 * j + 2, isbf) - ldin(xyz, 3 * i + 2, isbf);
        float dist = sqrtf(dx * dx + dy * dy + dz * dz + 3e-15f);
        if (dist < 5.0f) atomicAdd(&deg[i], 1);
    }
    if (idx < N128) {
        float v = ldin(cg_s, idx, isbf);
        s_acc[idx] = v;
        ushort_t hi = f2bf(v);
        s_hi[idx] = hi;
        s_lo[idx] = f2bf(v - bf2f(hi));
    }
    const int NW1 = 3 * 4 * 8 * 64;
    const int NW2 = 3 * 4 * 24 * 64;
    const int NWR = 3 * 24 * 64;
    if (idx < NW1) {
        int lane = idx & 63;
        int t = idx >> 6;
        int nt = t % 8; t /= 8;
        int ks = t % 4; int l = t / 4;
        int n = lane & 15, quad = lane >> 4;
        int col = nt * 16 + n;
        size_t base = (size_t)l * 128 * 128;
        size_t fo = (size_t)idx * 8;
        #pragma unroll
        for (int j = 0; j < 8; j++) {
            int k = ks * 32 + quad * 8 + j;
            float v = ldin(W1, base + (size_t)k * 128 + col, isbf);
            ushort_t hi = f2bf(v);
            B1hi[fo + j] = hi;
            B1lo[fo + j] = f2bf(v - bf2f(hi));
        }
    } else if (idx < NW1 + NW2) {
        int i2 = idx - NW1;
        int lane = i2 & 63;
        int t = i2 >> 6;
        int nt = t % 24; t /= 24;
        int ks = t % 4; int l = t / 4;
        int n = lane & 15, quad = lane >> 4;
        int col = nt * 16 + n;
        size_t base = (size_t)l * 128 * 384;
        size_t fo = (size_t)i2 * 8;
        #pragma unroll
        for (int j = 0; j < 8; j++) {
            int k = ks * 32 + quad * 8 + j;
            float v = ldin(W2, base + (size_t)k * 384 + col, isbf);
            ushort_t hi = f2bf(v);
            B2hi[fo + j] = hi;
            B2lo[fo + j] = f2bf(v - bf2f(hi));
        }
    } else if (idx < NW1 + NW2 + NWR) {
        int i2 = idx - NW1 - NW2;
        int lane = i2 & 63;
        int t = i2 >> 6;
        int nt = t % 24; int l = t / 24;
        int n = lane & 15, quad = lane >> 4;
        int col = nt * 16 + n;
        size_t fo = (size_t)i2 * 8;
        #pragma unroll
        for (int j = 0; j < 8; j++) {
            int k = quad * 8 + j;   // K=32: k<20 Wr, k==20 br, else 0
            float v = 0.f;
            if (k < NRBF) v = ldin(Wr, ((size_t)l * NRBF + k) * 384 + col, isbf);
            else if (k == NRBF) v = ldin(br, (size_t)l * 384 + col, isbf);
            ushort_t hi = f2bf(v);
            Wfhi[fo + j] = hi;
            Wflo[fo + j] = f2bf(v - bf2f(hi));
        }
    }
}

// ---------------- scan: rowptr from deg; deg becomes cursor ----------------
__global__ void scan_kernel(int* __restrict__ deg, int* __restrict__ rowptr, int N) {
    __shared__ int part[256];
    int t = threadIdx.x;
    int chunk = (N + 255) / 256;
    int lo = t * chunk, hi = min(lo + chunk, N);
    int s = 0;
    for (int i = lo; i < hi; i++) s += deg[i];
    part[t] = s;
    __syncthreads();
    for (int off = 1; off < 256; off <<= 1) {
        int v = (t >= off) ? part[t - off] : 0;
        __syncthreads();
        if (t >= off) part[t] += v;
        __syncthreads();
    }
    int base = (t == 0) ? 0 : part[t - 1];
    for (int i = lo; i < hi; i++) {
        rowptr[i] = base;
        int d = deg[i];
        deg[i] = base;
        base += d;
    }
    if (t == 0) rowptr[N] = part[255];
}

// ---------------- pack: geometry + CSR scatter (pos-ordered) ----------------
// rbf_aug[pos][32] hi/lo bf16: k<20 = rbf_k*env, k==20 = env, rest 0.
__global__ void pack_kernel(const void* __restrict__ xyz, const int* __restrict__ nbr,
                            int* __restrict__ cursor, int* __restrict__ jlist,
                            float4* __restrict__ upos,
                            ushort_t* __restrict__ rbfhi, ushort_t* __restrict__ rbflo,
                            int E, const int* __restrict__ flagp) {
    int isbf = *flagp;
    int e = blockIdx.x * blockDim.x + threadIdx.x;
    if (e >= E) return;
    int i = nbr[2 * e], j = nbr[2 * e + 1];
    float dx = ldin(xyz, 3 * j,     isbf) - ldin(xyz, 3 * i,     isbf);
    float dy = ldin(xyz, 3 * j + 1, isbf) - ldin(xyz, 3 * i + 1, isbf);
    float dz = ldin(xyz, 3 * j + 2, isbf) - ldin(xyz, 3 * i + 2, isbf);
    float dist = sqrtf(dx * dx + dy * dy + dz * dz + 3e-15f);
    if (!(dist < 5.0f)) return;
    constexpr float PI = 3.14159265358979323846f;
    float ev = 0.5f * (cosf(PI * dist * 0.2f) + 1.0f);
    int pos = atomicAdd(&cursor[i], 1);
    jlist[pos] = j;
    float inv = 1.0f / dist;
    upos[pos] = make_float4(dx * inv, dy * inv, dz * inv, ev);
    constexpr double EM5 = 0.006737946999085467;  // exp(-5)
    constexpr float MU0 = (float)EM5;
    constexpr float DMU = (float)((1.0 - EM5) / 19.0);
    constexpr float BETA = (float)(1.0 / ((0.1 * (1.0 - EM5)) * (0.1 * (1.0 - EM5))));
    float ed = expf(-dist);
    size_t rb = (size_t)pos * 32;
    #pragma unroll
    for (int k = 0; k < NRBF; k++) {
        float dmu = ed - (MU0 + k * DMU);
        float v = ev * expf(-BETA * dmu * dmu);
        ushort_t hi = f2bf(v);
        rbfhi[rb + k] = hi;
        rbflo[rb + k] = f2bf(v - bf2f(hi));
    }
    {   // augmented K-row 20 = env
        ushort_t hi = f2bf(ev);
        rbfhi[rb + NRBF] = hi;
        rbflo[rb + NRBF] = f2bf(ev - bf2f(hi));
    }
    #pragma unroll
    for (int k = NRBF + 1; k < 32; k++) { rbfhi[rb + k] = 0; rbflo[rb + k] = 0; }
}

// ---------------- fused GEMM1+GEMM2, y-split: phi = silu(s@W1+b1)@W2 + b2 --------
// grid (gx, 6): phase 1 computes full h (redundant per y), phase 2 does 4 ntiles.
__global__ __launch_bounds__(256) void gemm12_kernel(
    const ushort_t* __restrict__ s_hi, const ushort_t* __restrict__ s_lo,
    const ushort_t* __restrict__ B1hi, const ushort_t* __restrict__ B1lo,
    const void* __restrict__ b1, size_t b1off,
    const ushort_t* __restrict__ B2hi, const ushort_t* __restrict__ B2lo,
    const void* __restrict__ b2, size_t b2off,
    ushort_t* __restrict__ phi, int M, const int* __restrict__ flagp) {
    int isbf = *flagp;
    __shared__ ushort_t hhi[64][136];
    __shared__ ushort_t hlo[64][136];
    int tid = threadIdx.x;
    int wave = tid >> 6, lane = tid & 63;
    int m = lane & 15, quad = lane >> 4;
    int wr0 = wave * 16;
    int brow = blockIdx.x * 64;
    int row = brow + wr0 + m;
    short8 zero8 = {};
    {   // phase 1: h = silu(s@W1 + b1) -> LDS
        float4v acc1[8] = {};
        #pragma unroll
        for (int ks = 0; ks < 4; ks++) {
            short8 ah = zero8, al = zero8;
            if (row < M) {
                size_t ao = (size_t)row * 128 + ks * 32 + quad * 8;
                ah = *reinterpret_cast<const short8*>(s_hi + ao);
                al = *reinterpret_cast<const short8*>(s_lo + ao);
            }
            #pragma unroll
            for (int nt = 0; nt < 8; nt++) {
                size_t fo = (((size_t)ks * 8 + nt) * 64 + lane) * 8;
                short8 bh = *reinterpret_cast<const short8*>(B1hi + fo);
                acc1[nt] = __builtin_amdgcn_mfma_f32_16x16x32_bf16(ah, bh, acc1[nt], 0, 0, 0);
                acc1[nt] = __builtin_amdgcn_mfma_f32_16x16x32_bf16(al, bh, acc1[nt], 0, 0, 0);
                if (!isbf) {
                    short8 bl = *reinterpret_cast<const short8*>(B1lo + fo);
                    acc1[nt] = __builtin_amdgcn_mfma_f32_16x16x32_bf16(ah, bl, acc1[nt], 0, 0, 0);
                }
            }
        }
        #pragma unroll
        for (int nt = 0; nt < 8; nt++) {
            int col = nt * 16 + m;
            float bv = ldin(b1, b1off + col, isbf);
            #pragma unroll
            for (int r = 0; r < 4; r++) {
                int lrow = wr0 + quad * 4 + r;
                float x = acc1[nt][r] + bv;
                x = x / (1.0f + expf(-x));  // silu
                ushort_t h = f2bf(x);
                hhi[lrow][col] = h;
                hlo[lrow][col] = f2bf(x - bf2f(h));
            }
        }
    }
    __syncthreads();
    {   // phase 2: 4 ntiles of phi = h@W2 + b2
        int ntg0 = blockIdx.y * 4;
        float4v acc2[4] = {};
        #pragma unroll
        for (int ks = 0; ks < 4; ks++) {
            short8 ah = *reinterpret_cast<const short8*>(&hhi[wr0 + m][ks * 32 + quad * 8]);
            short8 al = *reinterpret_cast<const short8*>(&hlo[wr0 + m][ks * 32 + quad * 8]);
            #pragma unroll
            for (int nt = 0; nt < 4; nt++) {
                size_t fo = (((size_t)ks * 24 + ntg0 + nt) * 64 + lane) * 8;
                short8 bh = *reinterpret_cast<const short8*>(B2hi + fo);
                acc2[nt] = __builtin_amdgcn_mfma_f32_16x16x32_bf16(ah, bh, acc2[nt], 0, 0, 0);
                acc2[nt] = __builtin_amdgcn_mfma_f32_16x16x32_bf16(al, bh, acc2[nt], 0, 0, 0);
                if (!isbf) {
                    short8 bl = *reinterpret_cast<const short8*>(B2lo + fo);
                    acc2[nt] = __builtin_amdgcn_mfma_f32_16x16x32_bf16(ah, bl, acc2[nt], 0, 0, 0);
                }
            }
        }
        #pragma unroll
        for (int nt = 0; nt < 4; nt++) {
            int col = (ntg0 + nt) * 16 + m;
            float bv = ldin(b2, b2off + col, isbf);
            #pragma unroll
            for (int r = 0; r < 4; r++) {
                int orow = brow + wr0 + quad * 4 + r;
                if (orow < M) phi[(size_t)orow * 384 + col] = f2bf(acc2[nt][r] + bv);
            }
        }
    }
}

// ---------------- node kernel: barrier-free per-wave w-MFMA + gather ----------------
// Thread tt owns features {tt, 128+tt, 256+tt}. Wave w computes exactly the w-columns
// its own threads consume (ntiles seg*8 + w*4 + i) -> no cross-wave sync needed.
template <int L0, int LAST>
__global__ __launch_bounds__(128) void node_kernel(
    const int* __restrict__ rowptr, const int* __restrict__ jlist,
    const float4* __restrict__ upos,
    const ushort_t* __restrict__ rbfhi, const ushort_t* __restrict__ rbflo,
    const ushort_t* __restrict__ wfh, const ushort_t* __restrict__ wfl,
    const ushort_t* __restrict__ phi,
    const float* __restrict__ v_old, const ushort_t* __restrict__ vh_old,
    float* __restrict__ s_acc, ushort_t* __restrict__ s_hi, ushort_t* __restrict__ s_lo,
    float* __restrict__ v_new, ushort_t* __restrict__ vh_new,
    void* __restrict__ out, int N, const int* __restrict__ flagp) {
    int isbf = *flagp;
    __shared__ ushort_t wlds[16][396];   // stride 396: quads land on distinct bank octets
    int tt = threadIdx.x;
    int wave = tt >> 6, lane = tt & 63;
    int m = lane & 15, quad = lane >> 4;
    int node = blockIdx.x;
    int start = __builtin_amdgcn_readfirstlane(rowptr[node]);
    int end   = __builtin_amdgcn_readfirstlane(rowptr[node + 1]);
    float dsv = 0.f, ax = 0.f, ay = 0.f, az = 0.f;
    for (int c0 = start; c0 < end; c0 += 16) {
        int cnt = min(16, end - c0);
        int jv = (lane < cnt) ? jlist[c0 + lane] : 0;
        short8 arh = *reinterpret_cast<const short8*>(&rbfhi[(size_t)(c0 + m) * 32 + quad * 8]);
        float4v acc[12] = {};
        if (isbf) {
            #pragma unroll
            for (int s2 = 0; s2 < 12; s2++) {
                int nt = (s2 >> 2) * 8 + wave * 4 + (s2 & 3);
                short8 bh = *reinterpret_cast<const short8*>(wfh + ((size_t)nt * 64 + lane) * 8);
                acc[s2] = __builtin_amdgcn_mfma_f32_16x16x32_bf16(arh, bh, acc[s2], 0, 0, 0);
            }
        } else {
            short8 arl = *reinterpret_cast<const short8*>(&rbflo[(size_t)(c0 + m) * 32 + quad * 8]);
            #pragma unroll
            for (int s2 = 0; s2 < 12; s2++) {
                int nt = (s2 >> 2) * 8 + wave * 4 + (s2 & 3);
                size_t fo = ((size_t)nt * 64 + lane) * 8;
                short8 bh = *reinterpret_cast<const short8*>(wfh + fo);
                short8 bl = *reinterpret_cast<const short8*>(wfl + fo);
                acc[s2] = __builtin_amdgcn_mfma_f32_16x16x32_bf16(arh, bh, acc[s2], 0, 0, 0);
                acc[s2] = __builtin_amdgcn_mfma_f32_16x16x32_bf16(arl, bh, acc[s2], 0, 0, 0);
                acc[s2] = __builtin_amdgcn_mfma_f32_16x16x32_bf16(arh, bl, acc[s2], 0, 0, 0);
            }
        }
        #pragma unroll
        for (int s2 = 0; s2 < 12; s2++) {
            int col = ((s2 >> 2) * 8 + wave * 4 + (s2 & 3)) * 16 + m;
            #pragma unroll
            for (int r = 0; r < 4; r++)
                wlds[quad * 4 + r][col] = f2bf(acc[s2][r]);
        }
        // in-wave ordering only: each wave reads exactly what it wrote
        __asm__ volatile("s_waitcnt lgkmcnt(0)" ::: "memory");
        for (int k = 0; k < cnt; k++) {
            int j = __shfl(jv, k);
            float4 u4 = upos[c0 + k];
            float w0 = bf2f(wlds[k][tt]);
            float w1 = bf2f(wlds[k][128 + tt]);
            float w2 = bf2f(wlds[k][256 + tt]);
            size_t jb = (size_t)j * 384;
            dsv += bf2f(phi[jb + tt]) * w0;
            float gv = bf2f(phi[jb + 128 + tt]) * w1;
            float gu = bf2f(phi[jb + 256 + tt]) * w2;
            if (L0) {
                ax += gu * u4.x; ay += gu * u4.y; az += gu * u4.z;
            } else {
                const ushort_t* vj = &vh_old[jb + (size_t)tt * 3];
                ax += gu * u4.x + gv * bf2f(vj[0]);
                ay += gu * u4.y + gv * bf2f(vj[1]);
                az += gu * u4.z + gv * bf2f(vj[2]);
            }
        }
    }
    size_t so = (size_t)node * 128 + tt;
    float snew = s_acc[so] + dsv;
    size_t ib = (size_t)node * 384 + (size_t)tt * 3;
    float vx = L0 ? ax : v_old[ib]     + ax;
    float vy = L0 ? ay : v_old[ib + 1] + ay;
    float vz = L0 ? az : v_old[ib + 2] + az;
    if (LAST) {
        stout(out, so, snew, isbf);
        size_t ob = (size_t)N * 128 + ib;
        stout(out, ob,     vx, isbf);
        stout(out, ob + 1, vy, isbf);
        stout(out, ob + 2, vz, isbf);
    } else {
        s_acc[so] = snew;
        ushort_t hi = f2bf(snew);
        s_hi[so] = hi;
        s_lo[so] = f2bf(snew - bf2f(hi));
        v_new[ib] = vx; v_new[ib + 1] = vy; v_new[ib + 2] = vz;
        vh_new[ib]     = f2bf(vx);
        vh_new[ib + 1] = f2bf(vy);
        vh_new[ib + 2] = f2bf(vz);
    }
}

extern "C" void kernel_launch(void* const* d_in, const int* in_sizes, int n_in,
                              void* d_out, int out_size, void* d_ws, size_t ws_size,
                              hipStream_t stream) {
    const int N = in_sizes[0] / 3;
    const int E = in_sizes[1] / 2;
    const void* xyz  = d_in[0];
    const int*  nbr  = (const int*)d_in[1];
    const void* cg_s = d_in[2];
    const void* W1   = d_in[3];
    const void* b1   = d_in[4];
    const void* W2   = d_in[5];
    const void* b2   = d_in[6];
    const void* Wr   = d_in[7];
    const void* br   = d_in[8];

    size_t off = 0;
    auto alloc = [&](size_t bytes) -> char* {
        char* p = (char*)d_ws + off;
        off = (off + bytes + 63) & ~(size_t)63;
        return p;
    };
    int*      flag   = (int*)alloc(64);
    float*    s_acc  = (float*)alloc((size_t)N * 128 * 4);
    float*    vA     = (float*)alloc((size_t)N * 384 * 4);
    float*    vB     = (float*)alloc((size_t)N * 384 * 4);
    int*      rowptr = (int*)alloc((size_t)(N + 1) * 4);
    int*      deg    = (int*)alloc((size_t)N * 4);
    int*      jlist  = (int*)alloc((size_t)E * 4);
    float4*   upos   = (float4*)alloc((size_t)(E + 16) * 16);
    ushort_t* rbfhi  = (ushort_t*)alloc((size_t)(E + 16) * 32 * 2);
    ushort_t* rbflo  = (ushort_t*)alloc((size_t)(E + 16) * 32 * 2);
    ushort_t* s_hi   = (ushort_t*)alloc((size_t)N * 128 * 2);
    ushort_t* s_lo   = (ushort_t*)alloc((size_t)N * 128 * 2);
    ushort_t* phi    = (ushort_t*)alloc((size_t)N * 384 * 2);
    ushort_t* vhA    = (ushort_t*)alloc((size_t)N * 384 * 2);
    ushort_t* vhB    = (ushort_t*)alloc((size_t)N * 384 * 2);
    ushort_t* B1hi   = (ushort_t*)alloc((size_t)3 * 4 * 8 * 64 * 8 * 2);
    ushort_t* B1lo   = (ushort_t*)alloc((size_t)3 * 4 * 8 * 64 * 8 * 2);
    ushort_t* B2hi   = (ushort_t*)alloc((size_t)3 * 4 * 24 * 64 * 8 * 2);
    ushort_t* B2lo   = (ushort_t*)alloc((size_t)3 * 4 * 24 * 64 * 8 * 2);
    ushort_t* Wfhi   = (ushort_t*)alloc((size_t)3 * 24 * 64 * 8 * 2);
    ushort_t* Wflo   = (ushort_t*)alloc((size_t)3 * 24 * 64 * 8 * 2);

    detect_kernel<<<(N + 255) / 256, 256, 0, stream>>>(xyz, flag, deg, N);
    const int N128 = N * 128;
    const int pg = (max(E, N128) + 255) / 256;
    prelude_kernel<<<pg, 256, 0, stream>>>(xyz, nbr, cg_s, W1, W2, Wr, br,
                                           s_acc, s_hi, s_lo, deg,
                                           B1hi, B1lo, B2hi, B2lo, Wfhi, Wflo,
                                           N128, E, flag);
    scan_kernel<<<1, 256, 0, stream>>>(deg, rowptr, N);
    pack_kernel<<<(E + 255) / 256, 256, 0, stream>>>(xyz, nbr, deg, jlist, upos,
                                                     rbfhi, rbflo, E, flag);

    const int gx = (N + 63) / 64;
    for (int l = 0; l < 3; l++) {
        gemm12_kernel<<<dim3(gx, 6), 256, 0, stream>>>(
            s_hi, s_lo,
            B1hi + (size_t)l * 4 * 8 * 64 * 8, B1lo + (size_t)l * 4 * 8 * 64 * 8,
            b1, (size_t)l * 128,
            B2hi + (size_t)l * 4 * 24 * 64 * 8, B2lo + (size_t)l * 4 * 24 * 64 * 8,
            b2, (size_t)l * 384, phi, N, flag);
        const ushort_t* wfh = Wfhi + (size_t)l * 24 * 64 * 8;
        const ushort_t* wfl = Wflo + (size_t)l * 24 * 64 * 8;
        if (l == 0) {
            node_kernel<1, 0><<<N, 128, 0, stream>>>(
                rowptr, jlist, upos, rbfhi, rbflo, wfh, wfl, phi,
                vA, vhA, s_acc, s_hi, s_lo, vA, vhA, d_out, N, flag);
        } else if (l == 1) {
            node_kernel<0, 0><<<N, 128, 0, stream>>>(
                rowptr, jlist, upos, rbfhi, rbflo, wfh, wfl, phi,
                vA, vhA, s_acc, s_hi, s_lo, vB, vhB, d_out, N, flag);
        } else {
            node_kernel<0, 1><<<N, 128, 0, stream>>>(
                rowptr, jlist, upos, rbfhi, rbflo, wfh, wfl, phi,
                vB, vhB, s_acc, s_hi, s_lo, vB, vhB, d_out, N, flag);
        }
    }
}

// Round 8
// 406.614 us; speedup vs baseline: 1.6319x; 1.3274x over previous
//
#include <hip/hip_runtime.h>
#include <hip/hip_bf16.h>

#define NRBF 20
#define KAUG 24   // rbf(20) + env-row(20=bias) padded to 24

typedef __attribute__((ext_vector_type(8))) short short8;
typedef __attribute__((ext_vector_type(4))) float float4v;
typedef unsigned short ushort_t;

__device__ __forceinline__ float bf2f(ushort_t u) {
    return __uint_as_float(((unsigned)u) << 16);
}
__device__ __forceinline__ ushort_t f2bf(float f) {
    unsigned u = __float_as_uint(f);
    u += 0x7FFF + ((u >> 16) & 1);   // round-to-nearest-even
    return (ushort_t)(u >> 16);
}
__device__ __forceinline__ float ldin(const void* p, size_t idx, int isbf) {
    return isbf ? bf2f(((const ushort_t*)p)[idx]) : ((const float*)p)[idx];
}
__device__ __forceinline__ void stout(void* p, size_t idx, float v, int isbf) {
    if (isbf) ((ushort_t*)p)[idx] = f2bf(v);
    else      ((float*)p)[idx] = v;
}

// ---------------- dtype detect + deg zero (fused) ----------------
__global__ void detect_kernel(const void* __restrict__ xyz, int* __restrict__ flag,
                              int* __restrict__ deg, int N) {
    int idx = blockIdx.x * blockDim.x + threadIdx.x;
    if (idx < N) deg[idx] = 0;
    if (blockIdx.x == 0 && threadIdx.x < 64) {
        const ushort_t* u = (const ushort_t*)xyz;
        unsigned e0 = (u[2 * threadIdx.x] >> 7) & 0xFF;
        unsigned long long bad = __ballot(e0 >= 0x90);
        if (threadIdx.x == 0) *flag = (__popcll(bad) > 2) ? 0 : 1;  // 1=bf16, 0=f32
    }
}

// ---------------- prelude: deg count + s init + weight prep ----------------
// B1 frags [l][ks4][nt8][lane64][8]; B2 frags [l][ks4][nt24][lane64][8];
// WrT f32 [l][col384][KAUG]: k<20 = Wr[l][k][col], k==20 = br[l][col], else 0.
__global__ void prelude_kernel(const void* __restrict__ xyz, const int* __restrict__ nbr,
                               const void* __restrict__ cg_s,
                               const void* __restrict__ W1, const void* __restrict__ W2,
                               const void* __restrict__ Wr, const void* __restrict__ br,
                               float* __restrict__ s_acc, ushort_t* __restrict__ s_hi,
                               ushort_t* __restrict__ s_lo, int* __restrict__ deg,
                               ushort_t* __restrict__ B1hi, ushort_t* __restrict__ B1lo,
                               ushort_t* __restrict__ B2hi, ushort_t* __restrict__ B2lo,
                               float* __restrict__ WrT,
                               int N128, int E, const int* __restrict__ flagp) {
    int isbf = *flagp;
    int idx = blockIdx.x * blockDim.x + threadIdx.x;
    if (idx < E) {
        int i = nbr[2 * idx], j = nbr[2 * idx + 1];
        float dx = ldin(xyz, 3 * j,     isbf) - ldin(xyz, 3 * i,     isbf);
        float dy = ldin(xyz, 3 * j + 1, isbf) - ldin(xyz, 3 * i + 1, isbf);
        float dz = ldin(xyz, 3 * j + 2, isbf) - ldin(xyz, 3 * i + 2, isbf);
        float dist = sqrtf(dx * dx + dy * dy + dz * dz + 3e-15f);
        if (dist < 5.0f) atomicAdd(&deg[i], 1);
    }
    if (idx < N128) {
        float v = ldin(cg_s, idx, isbf);
        s_acc[idx] = v;
        ushort_t hi = f2bf(v);
        s_hi[idx] = hi;
        s_lo[idx] = f2bf(v - bf2f(hi));
    }
    const int NW1 = 3 * 4 * 8 * 64;
    const int NW2 = 3 * 4 * 24 * 64;
    const int NWT = 3 * 384;
    if (idx < NW1) {
        int lane = idx & 63;
        int t = idx >> 6;
        int nt = t % 8; t /= 8;
        int ks = t % 4; int l = t / 4;
        int n = lane & 15, quad = lane >> 4;
        int col = nt * 16 + n;
        size_t base = (size_t)l * 128 * 128;
        size_t fo = (size_t)idx * 8;
        #pragma unroll
        for (int j = 0; j < 8; j++) {
            int k = ks * 32 + quad * 8 + j;
            float v = ldin(W1, base + (size_t)k * 128 + col, isbf);
            ushort_t hi = f2bf(v);
            B1hi[fo + j] = hi;
            B1lo[fo + j] = f2bf(v - bf2f(hi));
        }
    } else if (idx < NW1 + NW2) {
        int i2 = idx - NW1;
        int lane = i2 & 63;
        int t = i2 >> 6;
        int nt = t % 24; t /= 24;
        int ks = t % 4; int l = t / 4;
        int n = lane & 15, quad = lane >> 4;
        int col = nt * 16 + n;
        size_t base = (size_t)l * 128 * 384;
        size_t fo = (size_t)i2 * 8;
        #pragma unroll
        for (int j = 0; j < 8; j++) {
            int k = ks * 32 + quad * 8 + j;
            float v = ldin(W2, base + (size_t)k * 384 + col, isbf);
            ushort_t hi = f2bf(v);
            B2hi[fo + j] = hi;
            B2lo[fo + j] = f2bf(v - bf2f(hi));
        }
    } else if (idx < NW1 + NW2 + NWT) {
        int i2 = idx - NW1 - NW2;
        int l = i2 / 384, col = i2 % 384;
        float* wt = WrT + ((size_t)l * 384 + col) * KAUG;
        #pragma unroll
        for (int k = 0; k < KAUG; k++) {
            float v = 0.f;
            if (k < NRBF) v = ldin(Wr, ((size_t)l * NRBF + k) * 384 + col, isbf);
            else if (k == NRBF) v = ldin(br, (size_t)l * 384 + col, isbf);
            wt[k] = v;
        }
    }
}

// ---------------- scan: rowptr from deg; deg becomes cursor ----------------
__global__ void scan_kernel(int* __restrict__ deg, int* __restrict__ rowptr, int N) {
    __shared__ int part[256];
    int t = threadIdx.x;
    int chunk = (N + 255) / 256;
    int lo = t * chunk, hi = min(lo + chunk, N);
    int s = 0;
    for (int i = lo; i < hi; i++) s += deg[i];
    part[t] = s;
    __syncthreads();
    for (int off = 1; off < 256; off <<= 1) {
        int v = (t >= off) ? part[t - off] : 0;
        __syncthreads();
        if (t >= off) part[t] += v;
        __syncthreads();
    }
    int base = (t == 0) ? 0 : part[t - 1];
    for (int i = lo; i < hi; i++) {
        rowptr[i] = base;
        int d = deg[i];
        deg[i] = base;
        base += d;
    }
    if (t == 0) rowptr[N] = part[255];
}

// ---------------- pack: geometry + CSR scatter (pos-ordered) ----------------
// jlist[pos]=j, upos[pos]=(ux,uy,uz,env), rbfp f32 [pos][KAUG]: k<20 = env*rbf_k,
// k==20 = env (bias row), else 0.
__global__ void pack_kernel(const void* __restrict__ xyz, const int* __restrict__ nbr,
                            int* __restrict__ cursor, int* __restrict__ jlist,
                            float4* __restrict__ upos, float* __restrict__ rbfp,
                            int E, const int* __restrict__ flagp) {
    int isbf = *flagp;
    int e = blockIdx.x * blockDim.x + threadIdx.x;
    if (e >= E) return;
    int i = nbr[2 * e], j = nbr[2 * e + 1];
    float dx = ldin(xyz, 3 * j,     isbf) - ldin(xyz, 3 * i,     isbf);
    float dy = ldin(xyz, 3 * j + 1, isbf) - ldin(xyz, 3 * i + 1, isbf);
    float dz = ldin(xyz, 3 * j + 2, isbf) - ldin(xyz, 3 * i + 2, isbf);
    float dist = sqrtf(dx * dx + dy * dy + dz * dz + 3e-15f);
    if (!(dist < 5.0f)) return;
    constexpr float PI = 3.14159265358979323846f;
    float ev = 0.5f * (cosf(PI * dist * 0.2f) + 1.0f);
    int pos = atomicAdd(&cursor[i], 1);
    jlist[pos] = j;
    float inv = 1.0f / dist;
    upos[pos] = make_float4(dx * inv, dy * inv, dz * inv, ev);
    constexpr double EM5 = 0.006737946999085467;  // exp(-5)
    constexpr float MU0 = (float)EM5;
    constexpr float DMU = (float)((1.0 - EM5) / 19.0);
    constexpr float BETA = (float)(1.0 / ((0.1 * (1.0 - EM5)) * (0.1 * (1.0 - EM5))));
    float ed = expf(-dist);
    float* rp = rbfp + (size_t)pos * KAUG;
    #pragma unroll
    for (int k = 0; k < NRBF; k++) {
        float dmu = ed - (MU0 + k * DMU);
        rp[k] = ev * expf(-BETA * dmu * dmu);
    }
    rp[NRBF] = ev;
    #pragma unroll
    for (int k = NRBF + 1; k < KAUG; k++) rp[k] = 0.f;
}

// ---------------- MFMA GEMM, 16-col y-tiles: C = act(A@B + bias) ----------------
// grid (ceil(M/64), ntiles). Block 256 = 4 waves; wave w owns rows bx*64+w*16.
// OUTMODE 0: write split hi/lo bf16; OUTMODE 1: write single bf16.
template <int ACT, int OUTMODE>
__global__ __launch_bounds__(256) void mfma_gemm(
    const ushort_t* __restrict__ Ahi, const ushort_t* __restrict__ Alo,
    const ushort_t* __restrict__ Bhi, const ushort_t* __restrict__ Blo,
    const void* __restrict__ bias, size_t biasoff,
    ushort_t* __restrict__ out_hi, ushort_t* __restrict__ out_lo,
    int M, int Ncols, const int* __restrict__ flagp) {
    int isbf = *flagp;
    int tid = threadIdx.x;
    int wave = tid >> 6, lane = tid & 63;
    int m = lane & 15, quad = lane >> 4;
    int brow = blockIdx.x * 64 + wave * 16;
    int row = brow + m;
    int ntiles = Ncols >> 4;
    int nt = blockIdx.y;
    float4v acc = {};
    short8 zero8 = {};
    #pragma unroll
    for (int ks = 0; ks < 4; ks++) {
        short8 ah = zero8, al = zero8;
        if (row < M) {
            size_t ao = (size_t)row * 128 + ks * 32 + quad * 8;
            ah = *reinterpret_cast<const short8*>(Ahi + ao);
            al = *reinterpret_cast<const short8*>(Alo + ao);
        }
        size_t fo = (((size_t)ks * ntiles + nt) * 64 + lane) * 8;
        short8 bh = *reinterpret_cast<const short8*>(Bhi + fo);
        acc = __builtin_amdgcn_mfma_f32_16x16x32_bf16(ah, bh, acc, 0, 0, 0);
        acc = __builtin_amdgcn_mfma_f32_16x16x32_bf16(al, bh, acc, 0, 0, 0);
        if (!isbf) {
            short8 bl = *reinterpret_cast<const short8*>(Blo + fo);
            acc = __builtin_amdgcn_mfma_f32_16x16x32_bf16(ah, bl, acc, 0, 0, 0);
        }
    }
    int col = nt * 16 + m;
    float bv = ldin(bias, biasoff + col, isbf);
    #pragma unroll
    for (int r = 0; r < 4; r++) {
        int orow = brow + quad * 4 + r;
        if (orow >= M) continue;
        float x = acc[r] + bv;
        if (ACT) x = x / (1.0f + expf(-x));  // silu
        size_t oo = (size_t)orow * Ncols + col;
        ushort_t h = f2bf(x);
        out_hi[oo] = h;
        if (OUTMODE == 0) out_lo[oo] = f2bf(x - bf2f(h));
    }
}

// ---------------- node gather kernel (r4 structure, proven) ----------------
// One block per node, 128 threads; thread tt owns features {tt, 128+tt, 256+tt}.
// w-dot over KAUG=21 real terms from transposed WrT (per-thread contiguous).
template <int L0, int LAST>
__global__ __launch_bounds__(128, 4) void node_kernel(
    const int* __restrict__ rowptr, const int* __restrict__ jlist,
    const float4* __restrict__ upos, const float* __restrict__ rbfp,
    const float* __restrict__ WrT,
    const ushort_t* __restrict__ phi,
    const float* __restrict__ v_old, const ushort_t* __restrict__ vh_old,
    float* __restrict__ s_acc, ushort_t* __restrict__ s_hi, ushort_t* __restrict__ s_lo,
    float* __restrict__ v_new, ushort_t* __restrict__ vh_new,
    void* __restrict__ out, int N, const int* __restrict__ flagp) {
    int isbf = *flagp;
    int tt = threadIdx.x;
    int node = blockIdx.x;

    // hoist this thread's 3 WrT columns (21 terms each, contiguous 84B)
    float wc0[NRBF + 1], wc1[NRBF + 1], wc2[NRBF + 1];
    {
        const float* w0p = WrT + (size_t)tt * KAUG;
        const float* w1p = WrT + (size_t)(tt + 128) * KAUG;
        const float* w2p = WrT + (size_t)(tt + 256) * KAUG;
        #pragma unroll
        for (int k = 0; k <= NRBF; k++) {
            wc0[k] = w0p[k]; wc1[k] = w1p[k]; wc2[k] = w2p[k];
        }
    }
    int start = __builtin_amdgcn_readfirstlane(rowptr[node]);
    int end   = __builtin_amdgcn_readfirstlane(rowptr[node + 1]);

    float dsv = 0.f, ax = 0.f, ay = 0.f, az = 0.f;
    for (int k = start; k < end; k++) {
        int j = __builtin_amdgcn_readfirstlane(jlist[k]);
        float4 u4 = upos[k];
        const float* rp = rbfp + (size_t)k * KAUG;
        float w0 = 0.f, w1 = 0.f, w2 = 0.f;
        #pragma unroll
        for (int r = 0; r <= NRBF; r++) {
            float rv = rp[r];
            w0 += rv * wc0[r];
            w1 += rv * wc1[r];
            w2 += rv * wc2[r];
        }
        size_t jb = (size_t)j * 384;
        dsv += bf2f(phi[jb + tt]) * w0;
        float gv = bf2f(phi[jb + 128 + tt]) * w1;
        float gu = bf2f(phi[jb + 256 + tt]) * w2;
        if (L0) {
            ax += gu * u4.x; ay += gu * u4.y; az += gu * u4.z;
        } else {
            const ushort_t* vj = &vh_old[jb + (size_t)tt * 3];
            ax += gu * u4.x + gv * bf2f(vj[0]);
            ay += gu * u4.y + gv * bf2f(vj[1]);
            az += gu * u4.z + gv * bf2f(vj[2]);
        }
    }
    size_t so = (size_t)node * 128 + tt;
    float snew = s_acc[so] + dsv;
    size_t ib = (size_t)node * 384 + (size_t)tt * 3;
    float vx = L0 ? ax : v_old[ib]     + ax;
    float vy = L0 ? ay : v_old[ib + 1] + ay;
    float vz = L0 ? az : v_old[ib + 2] + az;
    if (LAST) {
        stout(out, so, snew, isbf);
        size_t ob = (size_t)N * 128 + ib;
        stout(out, ob,     vx, isbf);
        stout(out, ob + 1, vy, isbf);
        stout(out, ob + 2, vz, isbf);
    } else {
        s_acc[so] = snew;
        ushort_t hi = f2bf(snew);
        s_hi[so] = hi;
        s_lo[so] = f2bf(snew - bf2f(hi));
        v_new[ib] = vx; v_new[ib + 1] = vy; v_new[ib + 2] = vz;
        vh_new[ib]     = f2bf(vx);
        vh_new[ib + 1] = f2bf(vy);
        vh_new[ib + 2] = f2bf(vz);
    }
}

extern "C" void kernel_launch(void* const* d_in, const int* in_sizes, int n_in,
                              void* d_out, int out_size, void* d_ws, size_t ws_size,
                              hipStream_t stream) {
    const int N = in_sizes[0] / 3;
    const int E = in_sizes[1] / 2;
    const void* xyz  = d_in[0];
    const int*  nbr  = (const int*)d_in[1];
    const void* cg_s = d_in[2];
    const void* W1   = d_in[3];
    const void* b1   = d_in[4];
    const void* W2   = d_in[5];
    const void* b2   = d_in[6];
    const void* Wr   = d_in[7];
    const void* br   = d_in[8];

    size_t off = 0;
    auto alloc = [&](size_t bytes) -> char* {
        char* p = (char*)d_ws + off;
        off = (off + bytes + 63) & ~(size_t)63;
        return p;
    };
    int*      flag   = (int*)alloc(64);
    float*    s_acc  = (float*)alloc((size_t)N * 128 * 4);
    float*    vA     = (float*)alloc((size_t)N * 384 * 4);
    float*    vB     = (float*)alloc((size_t)N * 384 * 4);
    int*      rowptr = (int*)alloc((size_t)(N + 1) * 4);
    int*      deg    = (int*)alloc((size_t)N * 4);
    int*      jlist  = (int*)alloc((size_t)E * 4);
    float4*   upos   = (float4*)alloc((size_t)(E + 16) * 16);
    float*    rbfp   = (float*)alloc((size_t)(E + 16) * KAUG * 4);
    float*    WrT    = (float*)alloc((size_t)3 * 384 * KAUG * 4);
    ushort_t* s_hi   = (ushort_t*)alloc((size_t)N * 128 * 2);
    ushort_t* s_lo   = (ushort_t*)alloc((size_t)N * 128 * 2);
    ushort_t* h_hi   = (ushort_t*)alloc((size_t)N * 128 * 2);
    ushort_t* h_lo   = (ushort_t*)alloc((size_t)N * 128 * 2);
    ushort_t* phi    = (ushort_t*)alloc((size_t)N * 384 * 2);
    ushort_t* vhA    = (ushort_t*)alloc((size_t)N * 384 * 2);
    ushort_t* vhB    = (ushort_t*)alloc((size_t)N * 384 * 2);
    ushort_t* B1hi   = (ushort_t*)alloc((size_t)3 * 4 * 8 * 64 * 8 * 2);
    ushort_t* B1lo   = (ushort_t*)alloc((size_t)3 * 4 * 8 * 64 * 8 * 2);
    ushort_t* B2hi   = (ushort_t*)alloc((size_t)3 * 4 * 24 * 64 * 8 * 2);
    ushort_t* B2lo   = (ushort_t*)alloc((size_t)3 * 4 * 24 * 64 * 8 * 2);

    detect_kernel<<<(N + 255) / 256, 256, 0, stream>>>(xyz, flag, deg, N);
    const int N128 = N * 128;
    const int pg = (max(E, N128) + 255) / 256;
    prelude_kernel<<<pg, 256, 0, stream>>>(xyz, nbr, cg_s, W1, W2, Wr, br,
                                           s_acc, s_hi, s_lo, deg,
                                           B1hi, B1lo, B2hi, B2lo, WrT,
                                           N128, E, flag);
    scan_kernel<<<1, 256, 0, stream>>>(deg, rowptr, N);
    pack_kernel<<<(E + 255) / 256, 256, 0, stream>>>(xyz, nbr, deg, jlist, upos,
                                                     rbfp, E, flag);

    const int gx = (N + 63) / 64;
    for (int l = 0; l < 3; l++) {
        mfma_gemm<1, 0><<<dim3(gx, 8), 256, 0, stream>>>(
            s_hi, s_lo,
            B1hi + (size_t)l * 4 * 8 * 64 * 8, B1lo + (size_t)l * 4 * 8 * 64 * 8,
            b1, (size_t)l * 128, h_hi, h_lo, N, 128, flag);
        mfma_gemm<0, 1><<<dim3(gx, 24), 256, 0, stream>>>(
            h_hi, h_lo,
            B2hi + (size_t)l * 4 * 24 * 64 * 8, B2lo + (size_t)l * 4 * 24 * 64 * 8,
            b2, (size_t)l * 384, phi, (ushort_t*)nullptr, N, 384, flag);
        const float* wrt = WrT + (size_t)l * 384 * KAUG;
        if (l == 0) {
            node_kernel<1, 0><<<N, 128, 0, stream>>>(
                rowptr, jlist, upos, rbfp, wrt, phi,
                vA, vhA, s_acc, s_hi, s_lo, vA, vhA, d_out, N, flag);
        } else if (l == 1) {
            node_kernel<0, 0><<<N, 128, 0, stream>>>(
                rowptr, jlist, upos, rbfp, wrt, phi,
                vA, vhA, s_acc, s_hi, s_lo, vB, vhB, d_out, N, flag);
        } else {
            node_kernel<0, 1><<<N, 128, 0, stream>>>(
                rowptr, jlist, upos, rbfp, wrt, phi,
                vB, vhB, s_acc, s_hi, s_lo, vB, vhB, d_out, N, flag);
        }
    }
}

// Round 9
// 327.217 us; speedup vs baseline: 2.0279x; 1.2426x over previous
//
#include <hip/hip_runtime.h>
#include <hip/hip_bf16.h>

#define NRBF 20
#define KAUG 24   // 20 rbf + env(bias row) + 3 zero pad, stored f16

typedef __attribute__((ext_vector_type(8))) short short8;
typedef __attribute__((ext_vector_type(4))) float float4v;
typedef __attribute__((ext_vector_type(2))) _Float16 half2v;
typedef unsigned short ushort_t;

__device__ __forceinline__ float bf2f(ushort_t u) {
    return __uint_as_float(((unsigned)u) << 16);
}
__device__ __forceinline__ ushort_t f2bf(float f) {
    unsigned u = __float_as_uint(f);
    u += 0x7FFF + ((u >> 16) & 1);   // round-to-nearest-even
    return (ushort_t)(u >> 16);
}
__device__ __forceinline__ float ldin(const void* p, size_t idx, int isbf) {
    return isbf ? bf2f(((const ushort_t*)p)[idx]) : ((const float*)p)[idx];
}
__device__ __forceinline__ void stout(void* p, size_t idx, float v, int isbf) {
    if (isbf) ((ushort_t*)p)[idx] = f2bf(v);
    else      ((float*)p)[idx] = v;
}
__device__ __forceinline__ float dot2(half2v a, half2v b, float c) {
#if __has_builtin(__builtin_amdgcn_fdot2)
    return __builtin_amdgcn_fdot2(a, b, c, false);
#else
    return c + (float)a.x * (float)b.x + (float)a.y * (float)b.y;
#endif
}

// ---------------- dtype detect + deg zero (fused) ----------------
__global__ void detect_kernel(const void* __restrict__ xyz, int* __restrict__ flag,
                              int* __restrict__ deg, int N) {
    int idx = blockIdx.x * blockDim.x + threadIdx.x;
    if (idx < N) deg[idx] = 0;
    if (blockIdx.x == 0 && threadIdx.x < 64) {
        const ushort_t* u = (const ushort_t*)xyz;
        unsigned e0 = (u[2 * threadIdx.x] >> 7) & 0xFF;
        unsigned long long bad = __ballot(e0 >= 0x90);
        if (threadIdx.x == 0) *flag = (__popcll(bad) > 2) ? 0 : 1;  // 1=bf16, 0=f32
    }
}

// ---------------- prelude: deg count + s init + weight prep ----------------
// B1 frags [l][ks4][nt8][lane64][8]; B2 frags [l][ks4][nt24][lane64][8];
// WrT f16 [l][col384][KAUG]: k<20 = Wr[l][k][col], k==20 = br[l][col], else 0.
__global__ void prelude_kernel(const void* __restrict__ xyz, const int* __restrict__ nbr,
                               const void* __restrict__ cg_s,
                               const void* __restrict__ W1, const void* __restrict__ W2,
                               const void* __restrict__ Wr, const void* __restrict__ br,
                               float* __restrict__ s_acc, ushort_t* __restrict__ s_hi,
                               ushort_t* __restrict__ s_lo, int* __restrict__ deg,
                               ushort_t* __restrict__ B1hi, ushort_t* __restrict__ B1lo,
                               ushort_t* __restrict__ B2hi, ushort_t* __restrict__ B2lo,
                               _Float16* __restrict__ WrT,
                               int N128, int E, const int* __restrict__ flagp) {
    int isbf = *flagp;
    int idx = blockIdx.x * blockDim.x + threadIdx.x;
    if (idx < E) {
        int i = nbr[2 * idx], j = nbr[2 * idx + 1];
        float dx = ldin(xyz, 3 * j,     isbf) - ldin(xyz, 3 * i,     isbf);
        float dy = ldin(xyz, 3 * j + 1, isbf) - ldin(xyz, 3 * i + 1, isbf);
        float dz = ldin(xyz, 3 * j + 2, isbf) - ldin(xyz, 3 * i + 2, isbf);
        float dist = sqrtf(dx * dx + dy * dy + dz * dz + 3e-15f);
        if (dist < 5.0f) atomicAdd(&deg[i], 1);
    }
    if (idx < N128) {
        float v = ldin(cg_s, idx, isbf);
        s_acc[idx] = v;
        ushort_t hi = f2bf(v);
        s_hi[idx] = hi;
        s_lo[idx] = f2bf(v - bf2f(hi));
    }
    const int NW1 = 3 * 4 * 8 * 64;
    const int NW2 = 3 * 4 * 24 * 64;
    const int NWT = 3 * 384;
    if (idx < NW1) {
        int lane = idx & 63;
        int t = idx >> 6;
        int nt = t % 8; t /= 8;
        int ks = t % 4; int l = t / 4;
        int n = lane & 15, quad = lane >> 4;
        int col = nt * 16 + n;
        size_t base = (size_t)l * 128 * 128;
        size_t fo = (size_t)idx * 8;
        #pragma unroll
        for (int j = 0; j < 8; j++) {
            int k = ks * 32 + quad * 8 + j;
            float v = ldin(W1, base + (size_t)k * 128 + col, isbf);
            ushort_t hi = f2bf(v);
            B1hi[fo + j] = hi;
            B1lo[fo + j] = f2bf(v - bf2f(hi));
        }
    } else if (idx < NW1 + NW2) {
        int i2 = idx - NW1;
        int lane = i2 & 63;
        int t = i2 >> 6;
        int nt = t % 24; t /= 24;
        int ks = t % 4; int l = t / 4;
        int n = lane & 15, quad = lane >> 4;
        int col = nt * 16 + n;
        size_t base = (size_t)l * 128 * 384;
        size_t fo = (size_t)i2 * 8;
        #pragma unroll
        for (int j = 0; j < 8; j++) {
            int k = ks * 32 + quad * 8 + j;
            float v = ldin(W2, base + (size_t)k * 384 + col, isbf);
            ushort_t hi = f2bf(v);
            B2hi[fo + j] = hi;
            B2lo[fo + j] = f2bf(v - bf2f(hi));
        }
    } else if (idx < NW1 + NW2 + NWT) {
        int i2 = idx - NW1 - NW2;
        int l = i2 / 384, col = i2 % 384;
        _Float16* wt = WrT + ((size_t)l * 384 + col) * KAUG;
        #pragma unroll
        for (int k = 0; k < KAUG; k++) {
            float v = 0.f;
            if (k < NRBF) v = ldin(Wr, ((size_t)l * NRBF + k) * 384 + col, isbf);
            else if (k == NRBF) v = ldin(br, (size_t)l * 384 + col, isbf);
            wt[k] = (_Float16)v;
        }
    }
}

// ---------------- scan: rowptr from deg; deg becomes cursor ----------------
__global__ void scan_kernel(int* __restrict__ deg, int* __restrict__ rowptr, int N) {
    __shared__ int part[256];
    int t = threadIdx.x;
    int chunk = (N + 255) / 256;
    int lo = t * chunk, hi = min(lo + chunk, N);
    int s = 0;
    for (int i = lo; i < hi; i++) s += deg[i];
    part[t] = s;
    __syncthreads();
    for (int off = 1; off < 256; off <<= 1) {
        int v = (t >= off) ? part[t - off] : 0;
        __syncthreads();
        if (t >= off) part[t] += v;
        __syncthreads();
    }
    int base = (t == 0) ? 0 : part[t - 1];
    for (int i = lo; i < hi; i++) {
        rowptr[i] = base;
        int d = deg[i];
        deg[i] = base;
        base += d;
    }
    if (t == 0) rowptr[N] = part[255];
}

// ---------------- pack: geometry + CSR scatter (pos-ordered) ----------------
// jlist[pos]=j, upos[pos]=(ux,uy,uz,env), rbfh f16 [pos][KAUG]: k<20 = env*rbf_k,
// k==20 = env (bias row), k>20 = 0.
__global__ void pack_kernel(const void* __restrict__ xyz, const int* __restrict__ nbr,
                            int* __restrict__ cursor, int* __restrict__ jlist,
                            float4* __restrict__ upos, _Float16* __restrict__ rbfh,
                            int E, const int* __restrict__ flagp) {
    int isbf = *flagp;
    int e = blockIdx.x * blockDim.x + threadIdx.x;
    if (e >= E) return;
    int i = nbr[2 * e], j = nbr[2 * e + 1];
    float dx = ldin(xyz, 3 * j,     isbf) - ldin(xyz, 3 * i,     isbf);
    float dy = ldin(xyz, 3 * j + 1, isbf) - ldin(xyz, 3 * i + 1, isbf);
    float dz = ldin(xyz, 3 * j + 2, isbf) - ldin(xyz, 3 * i + 2, isbf);
    float dist = sqrtf(dx * dx + dy * dy + dz * dz + 3e-15f);
    if (!(dist < 5.0f)) return;
    constexpr float PI = 3.14159265358979323846f;
    float ev = 0.5f * (cosf(PI * dist * 0.2f) + 1.0f);
    int pos = atomicAdd(&cursor[i], 1);
    jlist[pos] = j;
    float inv = 1.0f / dist;
    upos[pos] = make_float4(dx * inv, dy * inv, dz * inv, ev);
    constexpr double EM5 = 0.006737946999085467;  // exp(-5)
    constexpr float MU0 = (float)EM5;
    constexpr float DMU = (float)((1.0 - EM5) / 19.0);
    constexpr float BETA = (float)(1.0 / ((0.1 * (1.0 - EM5)) * (0.1 * (1.0 - EM5))));
    float ed = expf(-dist);
    _Float16* rp = rbfh + (size_t)pos * KAUG;
    #pragma unroll
    for (int k = 0; k < NRBF; k++) {
        float dmu = ed - (MU0 + k * DMU);
        rp[k] = (_Float16)(ev * expf(-BETA * dmu * dmu));
    }
    rp[NRBF] = (_Float16)ev;
    #pragma unroll
    for (int k = NRBF + 1; k < KAUG; k++) rp[k] = (_Float16)0.f;
}

// ---------------- MFMA GEMM, 1D swizzled grid for A-locality ----------------
// grid = ceil(M/64) * NTILES, 1D: nt = idx % NTILES (fast), bx = idx / NTILES
// -> consecutive blocks share the same 64 A-rows (L1/L2-hot); B frags are small.
template <int ACT, int OUTMODE, int NTILES>
__global__ __launch_bounds__(256) void mfma_gemm(
    const ushort_t* __restrict__ Ahi, const ushort_t* __restrict__ Alo,
    const ushort_t* __restrict__ Bhi, const ushort_t* __restrict__ Blo,
    const void* __restrict__ bias, size_t biasoff,
    ushort_t* __restrict__ out_hi, ushort_t* __restrict__ out_lo,
    int M, const int* __restrict__ flagp) {
    constexpr int Ncols = NTILES * 16;
    int isbf = *flagp;
    int nt = blockIdx.x % NTILES;
    int bx = blockIdx.x / NTILES;
    int tid = threadIdx.x;
    int wave = tid >> 6, lane = tid & 63;
    int m = lane & 15, quad = lane >> 4;
    int brow = bx * 64 + wave * 16;
    int row = brow + m;
    float4v acc = {};
    short8 zero8 = {};
    #pragma unroll
    for (int ks = 0; ks < 4; ks++) {
        short8 ah = zero8, al = zero8;
        if (row < M) {
            size_t ao = (size_t)row * 128 + ks * 32 + quad * 8;
            ah = *reinterpret_cast<const short8*>(Ahi + ao);
            al = *reinterpret_cast<const short8*>(Alo + ao);
        }
        size_t fo = (((size_t)ks * NTILES + nt) * 64 + lane) * 8;
        short8 bh = *reinterpret_cast<const short8*>(Bhi + fo);
        acc = __builtin_amdgcn_mfma_f32_16x16x32_bf16(ah, bh, acc, 0, 0, 0);
        acc = __builtin_amdgcn_mfma_f32_16x16x32_bf16(al, bh, acc, 0, 0, 0);
        if (!isbf) {
            short8 bl = *reinterpret_cast<const short8*>(Blo + fo);
            acc = __builtin_amdgcn_mfma_f32_16x16x32_bf16(ah, bl, acc, 0, 0, 0);
        }
    }
    int col = nt * 16 + m;
    float bv = ldin(bias, biasoff + col, isbf);
    #pragma unroll
    for (int r = 0; r < 4; r++) {
        int orow = brow + quad * 4 + r;
        if (orow >= M) continue;
        float x = acc[r] + bv;
        if (ACT) x = x / (1.0f + expf(-x));  // silu
        size_t oo = (size_t)orow * Ncols + col;
        ushort_t h = f2bf(x);
        out_hi[oo] = h;
        if (OUTMODE == 0) out_lo[oo] = f2bf(x - bf2f(h));
    }
}

// ---------------- node gather kernel (r4/r8 structure + f16 dot2 w-dot) ----------
// One block per node, 128 threads; thread tt owns features {tt, 128+tt, 256+tt}.
// w-dot: 11 half2 pairs (20 rbf + env/bias + zero pad) via v_dot2 -> 33 instr,
// wc registers = 33 half2 (fits VGPR budget, unlike 63 floats).
template <int L0, int LAST>
__global__ __launch_bounds__(128, 8) void node_kernel(
    const int* __restrict__ rowptr, const int* __restrict__ jlist,
    const float4* __restrict__ upos, const _Float16* __restrict__ rbfh,
    const _Float16* __restrict__ WrT,
    const ushort_t* __restrict__ phi,
    const float* __restrict__ v_old, const ushort_t* __restrict__ vh_old,
    float* __restrict__ s_acc, ushort_t* __restrict__ s_hi, ushort_t* __restrict__ s_lo,
    float* __restrict__ v_new, ushort_t* __restrict__ vh_new,
    void* __restrict__ out, int N, const int* __restrict__ flagp) {
    int isbf = *flagp;
    int tt = threadIdx.x;
    int node = blockIdx.x;

    // hoist this thread's 3 WrT columns: 11 half2 each (44B contiguous)
    half2v wc0[11], wc1[11], wc2[11];
    {
        const half2v* w0p = (const half2v*)(WrT + (size_t)tt * KAUG);
        const half2v* w1p = (const half2v*)(WrT + (size_t)(tt + 128) * KAUG);
        const half2v* w2p = (const half2v*)(WrT + (size_t)(tt + 256) * KAUG);
        #pragma unroll
        for (int k = 0; k < 11; k++) {
            wc0[k] = w0p[k]; wc1[k] = w1p[k]; wc2[k] = w2p[k];
        }
    }
    int start = __builtin_amdgcn_readfirstlane(rowptr[node]);
    int end   = __builtin_amdgcn_readfirstlane(rowptr[node + 1]);

    float dsv = 0.f, ax = 0.f, ay = 0.f, az = 0.f;
    for (int k = start; k < end; k++) {
        int j = __builtin_amdgcn_readfirstlane(jlist[k]);
        float4 u4 = upos[k];
        const half2v* rp = (const half2v*)(rbfh + (size_t)k * KAUG);
        float w0 = 0.f, w1 = 0.f, w2 = 0.f;
        #pragma unroll
        for (int r = 0; r < 11; r++) {
            half2v rv = rp[r];
            w0 = dot2(rv, wc0[r], w0);
            w1 = dot2(rv, wc1[r], w1);
            w2 = dot2(rv, wc2[r], w2);
        }
        size_t jb = (size_t)j * 384;
        dsv += bf2f(phi[jb + tt]) * w0;
        float gv = bf2f(phi[jb + 128 + tt]) * w1;
        float gu = bf2f(phi[jb + 256 + tt]) * w2;
        if (L0) {
            ax += gu * u4.x; ay += gu * u4.y; az += gu * u4.z;
        } else {
            const ushort_t* vj = &vh_old[jb + (size_t)tt * 3];
            ax += gu * u4.x + gv * bf2f(vj[0]);
            ay += gu * u4.y + gv * bf2f(vj[1]);
            az += gu * u4.z + gv * bf2f(vj[2]);
        }
    }
    size_t so = (size_t)node * 128 + tt;
    float snew = s_acc[so] + dsv;
    size_t ib = (size_t)node * 384 + (size_t)tt * 3;
    float vx = L0 ? ax : v_old[ib]     + ax;
    float vy = L0 ? ay : v_old[ib + 1] + ay;
    float vz = L0 ? az : v_old[ib + 2] + az;
    if (LAST) {
        stout(out, so, snew, isbf);
        size_t ob = (size_t)N * 128 + ib;
        stout(out, ob,     vx, isbf);
        stout(out, ob + 1, vy, isbf);
        stout(out, ob + 2, vz, isbf);
    } else {
        s_acc[so] = snew;
        ushort_t hi = f2bf(snew);
        s_hi[so] = hi;
        s_lo[so] = f2bf(snew - bf2f(hi));
        v_new[ib] = vx; v_new[ib + 1] = vy; v_new[ib + 2] = vz;
        vh_new[ib]     = f2bf(vx);
        vh_new[ib + 1] = f2bf(vy);
        vh_new[ib + 2] = f2bf(vz);
    }
}

extern "C" void kernel_launch(void* const* d_in, const int* in_sizes, int n_in,
                              void* d_out, int out_size, void* d_ws, size_t ws_size,
                              hipStream_t stream) {
    const int N = in_sizes[0] / 3;
    const int E = in_sizes[1] / 2;
    const void* xyz  = d_in[0];
    const int*  nbr  = (const int*)d_in[1];
    const void* cg_s = d_in[2];
    const void* W1   = d_in[3];
    const void* b1   = d_in[4];
    const void* W2   = d_in[5];
    const void* b2   = d_in[6];
    const void* Wr   = d_in[7];
    const void* br   = d_in[8];

    size_t off = 0;
    auto alloc = [&](size_t bytes) -> char* {
        char* p = (char*)d_ws + off;
        off = (off + bytes + 63) & ~(size_t)63;
        return p;
    };
    int*       flag   = (int*)alloc(64);
    float*     s_acc  = (float*)alloc((size_t)N * 128 * 4);
    float*     vA     = (float*)alloc((size_t)N * 384 * 4);
    float*     vB     = (float*)alloc((size_t)N * 384 * 4);
    int*       rowptr = (int*)alloc((size_t)(N + 1) * 4);
    int*       deg    = (int*)alloc((size_t)N * 4);
    int*       jlist  = (int*)alloc((size_t)E * 4);
    float4*    upos   = (float4*)alloc((size_t)(E + 16) * 16);
    _Float16*  rbfh   = (_Float16*)alloc((size_t)(E + 16) * KAUG * 2);
    _Float16*  WrT    = (_Float16*)alloc((size_t)3 * 384 * KAUG * 2);
    ushort_t*  s_hi   = (ushort_t*)alloc((size_t)N * 128 * 2);
    ushort_t*  s_lo   = (ushort_t*)alloc((size_t)N * 128 * 2);
    ushort_t*  h_hi   = (ushort_t*)alloc((size_t)N * 128 * 2);
    ushort_t*  h_lo   = (ushort_t*)alloc((size_t)N * 128 * 2);
    ushort_t*  phi    = (ushort_t*)alloc((size_t)N * 384 * 2);
    ushort_t*  vhA    = (ushort_t*)alloc((size_t)N * 384 * 2);
    ushort_t*  vhB    = (ushort_t*)alloc((size_t)N * 384 * 2);
    ushort_t*  B1hi   = (ushort_t*)alloc((size_t)3 * 4 * 8 * 64 * 8 * 2);
    ushort_t*  B1lo   = (ushort_t*)alloc((size_t)3 * 4 * 8 * 64 * 8 * 2);
    ushort_t*  B2hi   = (ushort_t*)alloc((size_t)3 * 4 * 24 * 64 * 8 * 2);
    ushort_t*  B2lo   = (ushort_t*)alloc((size_t)3 * 4 * 24 * 64 * 8 * 2);

    detect_kernel<<<(N + 255) / 256, 256, 0, stream>>>(xyz, flag, deg, N);
    const int N128 = N * 128;
    const int pg = (max(E, N128) + 255) / 256;
    prelude_kernel<<<pg, 256, 0, stream>>>(xyz, nbr, cg_s, W1, W2, Wr, br,
                                           s_acc, s_hi, s_lo, deg,
                                           B1hi, B1lo, B2hi, B2lo, WrT,
                                           N128, E, flag);
    scan_kernel<<<1, 256, 0, stream>>>(deg, rowptr, N);
    pack_kernel<<<(E + 255) / 256, 256, 0, stream>>>(xyz, nbr, deg, jlist, upos,
                                                     rbfh, E, flag);

    const int gx = (N + 63) / 64;
    for (int l = 0; l < 3; l++) {
        mfma_gemm<1, 0, 8><<<gx * 8, 256, 0, stream>>>(
            s_hi, s_lo,
            B1hi + (size_t)l * 4 * 8 * 64 * 8, B1lo + (size_t)l * 4 * 8 * 64 * 8,
            b1, (size_t)l * 128, h_hi, h_lo, N, flag);
        mfma_gemm<0, 1, 24><<<gx * 24, 256, 0, stream>>>(
            h_hi, h_lo,
            B2hi + (size_t)l * 4 * 24 * 64 * 8, B2lo + (size_t)l * 4 * 24 * 64 * 8,
            b2, (size_t)l * 384, phi, (ushort_t*)nullptr, N, flag);
        const _Float16* wrt = WrT + (size_t)l * 384 * KAUG;
        if (l == 0) {
            node_kernel<1, 0><<<N, 128, 0, stream>>>(
                rowptr, jlist, upos, rbfh, wrt, phi,
                vA, vhA, s_acc, s_hi, s_lo, vA, vhA, d_out, N, flag);
        } else if (l == 1) {
            node_kernel<0, 0><<<N, 128, 0, stream>>>(
                rowptr, jlist, upos, rbfh, wrt, phi,
                vA, vhA, s_acc, s_hi, s_lo, vB, vhB, d_out, N, flag);
        } else {
            node_kernel<0, 1><<<N, 128, 0, stream>>>(
                rowptr, jlist, upos, rbfh, wrt, phi,
                vB, vhB, s_acc, s_hi, s_lo, vB, vhB, d_out, N, flag);
        }
    }
}